// Round 9
// baseline (1165.841 us; speedup 1.0000x reference)
//
#include <hip/hip_runtime.h>
#include <math.h>

#define NN 4096
#define FF 128
#define CD 100
#define OT_ITERS 20
#define RVAL (1.0f/4096.0f)
#define EK 8192
#define KS 8
#define CHUNK 16
#define NCH 256

typedef unsigned int uint;
typedef __attribute__((ext_vector_type(8))) short bf16x8;
typedef __attribute__((ext_vector_type(4))) float f32x4;

// ---------- bf16 helpers ----------
__device__ __forceinline__ float bflo(uint u){ return __uint_as_float(u << 16); }
__device__ __forceinline__ float bfhi(uint u){ return __uint_as_float(u & 0xFFFF0000u); }
__device__ __forceinline__ unsigned short f2bf(float x){
  uint u = __float_as_uint(x);
  u += 0x7FFFu + ((u >> 16) & 1u);
  return (unsigned short)(u >> 16);
}
__device__ __forceinline__ void unpack8(uint4 kk, float* e){
  e[0]=bflo(kk.x); e[1]=bfhi(kk.x); e[2]=bflo(kk.y); e[3]=bfhi(kk.y);
  e[4]=bflo(kk.z); e[5]=bfhi(kk.z); e[6]=bflo(kk.w); e[7]=bfhi(kk.w);
}
__device__ __forceinline__ uint4 pack8(const float* e){
  union { unsigned short us[8]; uint4 u4; } pk;
#pragma unroll
  for (int k=0;k<8;++k) pk.us[k]=f2bf(e[k]);
  return pk.u4;
}

// ---------- 4-bit linear codec: K in [e^-1, 1]; K = A4 + B4*n, n in [0,15] ----------
#define A4 0.36787944f
#define B4 0.042141372f
#define INVB4 23.729603f
__device__ __forceinline__ uint e4(float f){
  float q = (f - A4) * INVB4;
  int n = (int)(q + 0.5f);
  n = n < 0 ? 0 : (n > 15 ? 15 : n);
  return (uint)n;
}
__device__ __forceinline__ void d4x8(uint w, float* e){
#pragma unroll
  for (int k=0;k<8;++k)
    e[k] = A4 + B4 * (float)((w >> (4*k)) & 15u);
}

// ---------- wave/block reduce helpers (wave = 64) ----------
__device__ __forceinline__ float waveSum(float v){
#pragma unroll
  for (int o=32;o>0;o>>=1) v += __shfl_down(v,o);
  return v;
}
__device__ __forceinline__ float waveMax(float v){
#pragma unroll
  for (int o=32;o>0;o>>=1) v = fmaxf(v,__shfl_down(v,o));
  return v;
}
__device__ __forceinline__ float waveMin(float v){
#pragma unroll
  for (int o=32;o>0;o>>=1) v = fminf(v,__shfl_down(v,o));
  return v;
}
__device__ __forceinline__ float blkSum(float v, float* red){
  v = waveSum(v);
  if ((threadIdx.x&63)==0) red[threadIdx.x>>6] = v;
  __syncthreads();
  float r = red[0]+red[1]+red[2]+red[3];
  __syncthreads();
  return r;
}

// ---------- W transpose+convert: Wt[n][k] bf16 from W[k][n] fp32 ----------
__global__ __launch_bounds__(256) void transposeW(const float* __restrict__ W,
                                                  unsigned short* __restrict__ Wt)
{
  __shared__ unsigned short T[128][72];
  const int k0 = blockIdx.x*64, tid = threadIdx.x;
#pragma unroll
  for (int it=0; it<8; ++it){
    int f = tid + it*256;
    int r = f >> 5, c4 = f & 31;
    float4 v = *(const float4*)&W[(size_t)(k0+r)*FF + c4*4];
    T[c4*4+0][r]=f2bf(v.x); T[c4*4+1][r]=f2bf(v.y);
    T[c4*4+2][r]=f2bf(v.z); T[c4*4+3][r]=f2bf(v.w);
  }
  __syncthreads();
#pragma unroll
  for (int it=0; it<4; ++it){
    int f = tid + it*256;
    int n = f >> 3, c8 = f & 7;
    *(uint4*)&Wt[(size_t)n*EK + k0 + c8*8] = *(uint4*)&T[n][c8*8];
  }
}

// ---------- MFMA embed GEMM (split-K=8): part[ks][4096][128] ----------
__global__ __launch_bounds__(256) void embed_mfma(const float* __restrict__ A,
                                                  const unsigned short* __restrict__ Wt,
                                                  float* __restrict__ part)
{
  __shared__ unsigned short Al[64][72];
  __shared__ unsigned short Wl[128][72];
  const int tid = threadIdx.x;
  const int m0 = blockIdx.x * 64;
  const int kc = blockIdx.y * (EK/KS);
  const int w = tid >> 6, l = tid & 63;
  const int wr = w >> 1, wc = w & 1;
  const int lrow = l & 15, lk = (l >> 4) * 8;
  f32x4 acc[2][4];
#pragma unroll
  for (int mi=0;mi<2;++mi)
#pragma unroll
    for (int ni=0;ni<4;++ni) acc[mi][ni] = (f32x4){0.f,0.f,0.f,0.f};

  for (int k0 = kc; k0 < kc + EK/KS; k0 += 64) {
#pragma unroll
    for (int it = 0; it < 4; ++it) {
      int f = tid + it*256;
      int r = f >> 4, c4 = f & 15;
      float4 a4 = *(const float4*)&A[(size_t)(m0+r)*EK + k0 + c4*4];
      union { unsigned short us[4]; uint2 u2; } pk;
      pk.us[0]=f2bf(a4.x); pk.us[1]=f2bf(a4.y); pk.us[2]=f2bf(a4.z); pk.us[3]=f2bf(a4.w);
      *(uint2*)&Al[r][c4*4] = pk.u2;
    }
#pragma unroll
    for (int it = 0; it < 4; ++it) {
      int f = tid + it*256;
      int r = f >> 3, c8 = f & 7;
      *(uint4*)&Wl[r][c8*8] = *(const uint4*)&Wt[(size_t)r*EK + k0 + c8*8];
    }
    __syncthreads();
#pragma unroll
    for (int ksub = 0; ksub < 2; ++ksub) {
      bf16x8 af[2], bfr[4];
#pragma unroll
      for (int mi=0;mi<2;++mi) af[mi] = *(bf16x8*)&Al[wr*32+mi*16+lrow][ksub*32+lk];
#pragma unroll
      for (int ni=0;ni<4;++ni) bfr[ni] = *(bf16x8*)&Wl[wc*64+ni*16+lrow][ksub*32+lk];
#pragma unroll
      for (int mi=0;mi<2;++mi)
#pragma unroll
        for (int ni=0;ni<4;++ni)
          acc[mi][ni] = __builtin_amdgcn_mfma_f32_16x16x32_bf16(af[mi], bfr[ni], acc[mi][ni], 0,0,0);
    }
    __syncthreads();
  }
#pragma unroll
  for (int mi=0;mi<2;++mi)
#pragma unroll
    for (int ni=0;ni<4;++ni)
#pragma unroll
      for (int r=0;r<4;++r) {
        int row = m0 + wr*32 + mi*16 + (l>>4)*4 + r;
        int col = wc*64 + ni*16 + lrow;
        part[((size_t)blockIdx.y*NN + row)*FF + col] = acc[mi][ni][r];
      }
}

// ---------- reduce split-K partials + bias + l2norm -> fp32 and bf16 ----------
__global__ __launch_bounds__(128) void reduce_l2(const float* __restrict__ part,
                                                 const float* __restrict__ bias,
                                                 float* __restrict__ out,
                                                 unsigned short* __restrict__ outb)
{
  __shared__ float red[2];
  int i = blockIdx.x, t = threadIdx.x;
  float s = bias[t];
#pragma unroll
  for (int ks=0; ks<KS; ++ks) s += part[((size_t)ks*NN + i)*FF + t];
  float q = waveSum(s*s);
  if ((t&63)==0) red[t>>6]=q;
  __syncthreads();
  float val = s / sqrtf(red[0]+red[1]);
  out[(size_t)i*FF+t] = val;
  outb[(size_t)i*FF+t] = f2bf(val);
}

// ---------- softmax rows of l[4096x100] -> S, w = ||S_row|| ----------
__global__ __launch_bounds__(128) void softmax_rows(const float* __restrict__ l,
                                                    float* __restrict__ S,
                                                    float* __restrict__ w)
{
  __shared__ float sm[2], ss[2], sq[2];
  int i = blockIdx.x, t = threadIdx.x;
  int lane = t & 63, wid = t >> 6;
  float x = (t < CD) ? l[(size_t)i*CD + t] : -3.4e38f;
  float m = waveMax(x);
  if (lane==0) sm[wid]=m;
  __syncthreads();
  m = fmaxf(sm[0], sm[1]);
  float e = (t < CD) ? __expf(x - m) : 0.f;
  float s = waveSum(e);
  if (lane==0) ss[wid]=s;
  __syncthreads();
  float tot = ss[0]+ss[1];
  float sv = e / tot;
  if (t < CD) S[(size_t)i*CD + t] = sv;
  float q = waveSum(sv*sv);
  if (lane==0) sq[wid]=q;
  __syncthreads();
  if (t==0) w[i] = sqrtf(sq[0]+sq[1]);
}

// ---------- cos matrix: D[i][j] = (S_i . S_j)/max(w_i w_j, eps), diag = -2 ----------
// Bs stride 67 (odd words): transpose-store ~3-way instead of ~11-way conflicts
__global__ __launch_bounds__(256) void cos_gemm(const float* __restrict__ S,
                                                const float* __restrict__ w,
                                                float* __restrict__ D)
{
  __shared__ float As[64][108];
  __shared__ float Bs[100][67];
  const int tid = threadIdx.x;
  const int tc = tid & 15, tr = tid >> 4;
  const int i0 = blockIdx.y*64, j0 = blockIdx.x*64;
  for (int f = tid; f < 64*25; f += 256){
    int r = f/25, c4 = f%25;
    *(float4*)&As[r][c4*4] = *(const float4*)&S[(size_t)(i0+r)*CD + c4*4];
  }
  for (int f = tid; f < 64*25; f += 256){
    int r = f/25, c4 = f%25;
    float4 bv = *(const float4*)&S[(size_t)(j0+r)*CD + c4*4];
    Bs[c4*4+0][r]=bv.x; Bs[c4*4+1][r]=bv.y; Bs[c4*4+2][r]=bv.z; Bs[c4*4+3][r]=bv.w;
  }
  __syncthreads();
  float acc[4][4];
#pragma unroll
  for (int a=0;a<4;++a)
#pragma unroll
    for (int b=0;b<4;++b) acc[a][b]=0.f;
  for (int kk=0; kk<100; kk+=4){
    float a[4][4];
#pragma unroll
    for (int q=0;q<4;++q) *(float4*)a[q] = *(const float4*)&As[tr*4+q][kk];
#pragma unroll
    for (int t4=0;t4<4;++t4){
      float b0 = Bs[kk+t4][tc*4+0];
      float b1 = Bs[kk+t4][tc*4+1];
      float b2 = Bs[kk+t4][tc*4+2];
      float b3 = Bs[kk+t4][tc*4+3];
#pragma unroll
      for (int rr=0;rr<4;++rr){
        float av = a[rr][t4];
        acc[rr][0] += av*b0; acc[rr][1] += av*b1;
        acc[rr][2] += av*b2; acc[rr][3] += av*b3;
      }
    }
  }
  float wi[4], wj[4];
#pragma unroll
  for (int q=0;q<4;++q){ wi[q] = w[i0+tr*4+q]; wj[q] = w[j0+tc*4+q]; }
#pragma unroll
  for (int rr=0;rr<4;++rr){
    int i = i0+tr*4+rr;
    float4 o;
    float* op = (float*)&o;
#pragma unroll
    for (int cc=0;cc<4;++cc){
      int j = j0+tc*4+cc;
      float val = acc[rr][cc] / fmaxf(wi[rr]*wj[cc], 1e-7f);
      op[cc] = (i==j) ? -2.f : val;
    }
    *(float4*)&D[(size_t)i*NN + j0 + tc*4] = o;
  }
}

// ---------- top-7 select per row of D; idx[i][0] = i ----------
__global__ __launch_bounds__(256) void knn_select(const float* __restrict__ D,
                                                  int* __restrict__ idx)
{
  __shared__ float redv[256];
  __shared__ int   redi[256];
  int i = blockIdx.x, tid = threadIdx.x;
  float bv[7]; int bi[7];
#pragma unroll
  for (int m=0;m<7;++m){ bv[m]=-3.4e38f; bi[m]=-1; }
  const float4* row4 = (const float4*)&D[(size_t)i*NN];
#pragma unroll
  for (int s=0;s<4;++s){
    int j4 = tid + s*256;
    float4 vv = row4[j4];
    float cv[4] = {vv.x, vv.y, vv.z, vv.w};
#pragma unroll
    for (int q=0;q<4;++q){
      if (cv[q] > bv[6]) {
        int m = 6;
        while (m > 0 && cv[q] > bv[m-1]) { bv[m]=bv[m-1]; bi[m]=bi[m-1]; --m; }
        bv[m]=cv[q]; bi[m]=j4*4+q;
      }
    }
  }
  if (tid==0) idx[(size_t)i*8] = i;
  for (int m=0;m<7;++m) {
    redv[tid]=bv[0]; redi[tid]=tid;
    __syncthreads();
    for (int s=128;s>=1;s>>=1) {
      if (tid < s) {
        if (redv[tid+s] > redv[tid]) { redv[tid]=redv[tid+s]; redi[tid]=redi[tid+s]; }
      }
      __syncthreads();
    }
    int wt = redi[0];
    if (tid == wt) {
      idx[(size_t)i*8 + 1 + m] = bi[0];
#pragma unroll
      for (int q=0;q<6;++q){ bv[q]=bv[q+1]; bi[q]=bi[q+1]; }
      bv[6]=-3.4e38f; bi[6]=-1;
    }
    __syncthreads();
  }
}

// ---------- encoder: outb = bf16(l2norm(concat(h, mean(h[idx])) @ W + b)) ----------
__global__ __launch_bounds__(128) void encoder_kernel(const float* __restrict__ h,
                                                      const int* __restrict__ idx,
                                                      const float* __restrict__ W,
                                                      const float* __restrict__ bias,
                                                      unsigned short* __restrict__ outb)
{
  __shared__ float hin[256];
  __shared__ float sred[2];
  int i = blockIdx.x, t = threadIdx.x;
  float hv = h[(size_t)i*FF + t];
  float agg = 0.f;
#pragma unroll
  for (int m=0;m<8;++m) agg += h[(size_t)idx[i*8+m]*FF + t];
  agg *= 0.125f;
  hin[t] = hv; hin[FF + t] = agg;
  __syncthreads();
  float acc = bias[t];
  for (int k=0;k<256;++k) acc += hin[k] * W[(size_t)k*FF + t];
  float s = waveSum(acc*acc);
  int lane = t & 63, wid = t >> 6;
  if (lane==0) sred[wid]=s;
  __syncthreads();
  float tot = sred[0]+sred[1];
  outb[(size_t)i*FF + t] = f2bf(acc / sqrtf(tot));
}

// ---------- MFMA: stage bf16 = A bf16 [4096x128] @ B^T ----------
__global__ __launch_bounds__(256) void gemm_btb_mfma(const unsigned short* __restrict__ A,
                                                     const unsigned short* __restrict__ B,
                                                     unsigned short* __restrict__ C)
{
  __shared__ unsigned short Al[64][136];
  __shared__ unsigned short Bl[64][136];
  const int tid = threadIdx.x;
  const int i0 = blockIdx.y*64, j0 = blockIdx.x*64;
#pragma unroll
  for (int it=0; it<4; ++it){
    int f = tid + it*256;
    int r = f >> 4, c8 = f & 15;
    *(uint4*)&Al[r][c8*8] = *(const uint4*)&A[(size_t)(i0+r)*FF + c8*8];
    *(uint4*)&Bl[r][c8*8] = *(const uint4*)&B[(size_t)(j0+r)*FF + c8*8];
  }
  __syncthreads();
  const int w = tid>>6, l = tid&63;
  const int wr = w>>1, wc = w&1;
  const int lrow = l&15, lk = (l>>4)*8;
  f32x4 acc[2][2];
#pragma unroll
  for (int mi=0;mi<2;++mi)
#pragma unroll
    for (int ni=0;ni<2;++ni) acc[mi][ni] = (f32x4){0.f,0.f,0.f,0.f};
#pragma unroll
  for (int ks=0; ks<4; ++ks){
    bf16x8 af[2], bfm[2];
#pragma unroll
    for (int mi=0;mi<2;++mi) af[mi] = *(bf16x8*)&Al[wr*32+mi*16+lrow][ks*32+lk];
#pragma unroll
    for (int ni=0;ni<2;++ni) bfm[ni] = *(bf16x8*)&Bl[wc*32+ni*16+lrow][ks*32+lk];
#pragma unroll
    for (int mi=0;mi<2;++mi)
#pragma unroll
      for (int ni=0;ni<2;++ni)
        acc[mi][ni] = __builtin_amdgcn_mfma_f32_16x16x32_bf16(af[mi], bfm[ni], acc[mi][ni], 0,0,0);
  }
  __syncthreads();
  unsigned short (*Cl)[72] = (unsigned short(*)[72])&Al[0][0];
#pragma unroll
  for (int mi=0;mi<2;++mi)
#pragma unroll
    for (int ni=0;ni<2;++ni)
#pragma unroll
      for (int r=0;r<4;++r){
        int row = wr*32 + mi*16 + (l>>4)*4 + r;
        int col = wc*32 + ni*16 + lrow;
        Cl[row][col] = f2bf(acc[mi][ni][r]);
      }
  __syncthreads();
#pragma unroll
  for (int it=0; it<2; ++it){
    int f = tid + it*256;
    int r = f >> 3, c8 = f & 7;
    *(uint4*)&C[(size_t)(i0+r)*NN + j0 + c8*8] = *(uint4*)&Cl[r][c8*8];
  }
}

// ---------- single-matrix per-row max/min over bf16 stage ----------
__global__ __launch_bounds__(256) void rowstat_s(const unsigned short* __restrict__ stage,
                                                 float* __restrict__ rmax,
                                                 float* __restrict__ rmin)
{
  __shared__ float r1[4], r2[4];
  int i = blockIdx.x, t = threadIdx.x;
  const uint4* row = (const uint4*)(stage + (size_t)i*NN);
  float mx=-3.4e38f, mn=3.4e38f;
#pragma unroll
  for (int s=0;s<2;++s){
    float e[8]; unpack8(row[t + s*256], e);
#pragma unroll
    for (int k=0;k<8;++k){ mx = fmaxf(mx,e[k]); mn = fminf(mn,e[k]); }
  }
  mx = waveMax(mx); mn = waveMin(mn);
  int lane = t & 63, wid = t >> 6;
  if (lane==0){ r1[wid]=mx; r2[wid]=mn; }
  __syncthreads();
  if (t==0){
    rmax[i] = fmaxf(fmaxf(r1[0],r1[1]),fmaxf(r1[2],r1[3]));
    rmin[i] = fminf(fminf(r2[0],r2[1]),fminf(r2[2],r2[3]));
  }
}

// ---------- single-matrix stat finalize: stat = {gmin, 1/(gmax-gmin)} ----------
__global__ __launch_bounds__(256) void greduce_s(const float* __restrict__ rmax,
                                                 const float* __restrict__ rmin,
                                                 float* __restrict__ stat)
{
  __shared__ float r1[4], r2[4];
  int t = threadIdx.x;
  float mx=-3.4e38f, mn=3.4e38f;
  for (int i=t; i<NN; i+=256){
    mx = fmaxf(mx, rmax[i]);
    mn = fminf(mn, rmin[i]);
  }
  mx = waveMax(mx); mn = waveMin(mn);
  int lane = t & 63, wid = t >> 6;
  if (lane==0){ r1[wid]=mx; r2[wid]=mn; }
  __syncthreads();
  if (t==0){
    float gmx = fmaxf(fmaxf(r1[0],r1[1]),fmaxf(r1[2],r1[3]));
    float gmn = fminf(fminf(r2[0],r2[1]),fminf(r2[2],r2[3]));
    stat[0] = gmn;
    stat[1] = 1.f/(gmx-gmn);
  }
}

// ---------- single-matrix: K4 = 4bit(exp((M0 - rowmax)*scale)); optional M out ----------
__global__ __launch_bounds__(256) void transform_s(const unsigned short* __restrict__ stage,
                                                   uint* __restrict__ K4m,
                                                   const float* __restrict__ rmax,
                                                   const float* __restrict__ stat,
                                                   float* __restrict__ Mout)
{
  const float gmin = stat[0], scale = stat[1];
  const uint4* Km = (const uint4*)stage;
  const bool wM = (Mout != nullptr);
  const int total8 = (NN*NN)/8;
  for (int f = blockIdx.x*256 + threadIdx.x; f < total8; f += 256*256){
    int i = f >> 9;
    float rm = rmax[i];
    float e[8]; unpack8(Km[f], e);
    uint o = 0;
#pragma unroll
    for (int k=0;k<8;++k) o |= e4(__expf((e[k]-rm)*scale)) << (4*k);
    K4m[f] = o;
    if (wM){
      float4 o1, o2;
      o1.x=(e[0]-gmin)*scale; o1.y=(e[1]-gmin)*scale; o1.z=(e[2]-gmin)*scale; o1.w=(e[3]-gmin)*scale;
      o2.x=(e[4]-gmin)*scale; o2.y=(e[5]-gmin)*scale; o2.z=(e[6]-gmin)*scale; o2.w=(e[7]-gmin)*scale;
      float4* mp = (float4*)(Mout + (size_t)f*8);
      mp[0]=o1; mp[1]=o2;
    }
  }
}

// ---------- init: v=1 for all 4 matrices ----------
__global__ void vinit4(float* __restrict__ v)
{
  int g = blockIdx.x*256 + threadIdx.x;
  if (g < 4*NN) v[g] = 1.f;
}

// ---------- fused sinkhorn iteration over 4-bit K (batched 4 matrices) ----------
__global__ __launch_bounds__(256) void sink_fused(const uint* __restrict__ K4base,
                                                  const float* __restrict__ vv,
                                                  unsigned short* __restrict__ part)
{
  __shared__ float red[4];
  const int m = blockIdx.y, b = blockIdx.x, t = threadIdx.x;
  const int i0 = b*CHUNK;
  const uint* K4 = K4base + (size_t)m*NN*(NN/8);
  const float4* v4 = (const float4*)(vv + (size_t)m*NN);
  float vs[16];
  {
    float4 A=v4[t*4+0], B=v4[t*4+1], C=v4[t*4+2], D=v4[t*4+3];
    vs[0]=A.x; vs[1]=A.y; vs[2]=A.z; vs[3]=A.w;
    vs[4]=B.x; vs[5]=B.y; vs[6]=B.z; vs[7]=B.w;
    vs[8]=C.x; vs[9]=C.y; vs[10]=C.z; vs[11]=C.w;
    vs[12]=D.x; vs[13]=D.y; vs[14]=D.z; vs[15]=D.w;
  }
  float colacc[16];
#pragma unroll
  for (int k=0;k<16;++k) colacc[k]=0.f;
  for (int r=0;r<CHUNK;++r){
    uint2 kw = ((const uint2*)(K4 + (size_t)(i0+r)*(NN/8)))[t];
    float e[16];
    d4x8(kw.x, e); d4x8(kw.y, e+8);
    float dot = 0.f;
#pragma unroll
    for (int k=0;k<16;++k) dot += e[k]*vs[k];
    float rowsum = blkSum(dot, red);
    float ur = RVAL / rowsum;
#pragma unroll
    for (int k=0;k<16;++k) colacc[k] += e[k]*ur;
  }
  unsigned short* prow = part + ((size_t)m*NCH + b)*NN;
  ((uint4*)prow)[t*2]   = pack8(colacc);
  ((uint4*)prow)[t*2+1] = pack8(colacc+8);
}

// ---------- column finish: v[j] = R / sum_b part[m][b][j]; 64 cols/block ----------
__global__ __launch_bounds__(256) void colfin_b(const unsigned short* __restrict__ part,
                                                float* __restrict__ vv)
{
  __shared__ float lds[32][8][9];
  const int m = blockIdx.y, bx = blockIdx.x, t = threadIdx.x;
  const int g = t & 7;           // uint4-group within 64 cols
  const int tq = t >> 3;         // 0..31 chunk-threads
  const uint4* pb = (const uint4*)(part + (size_t)m*NCH*NN);
  float acc[8];
#pragma unroll
  for (int k=0;k<8;++k) acc[k]=0.f;
#pragma unroll
  for (int s=0;s<8;++s){
    int b = tq + s*32;
    float e[8]; unpack8(pb[(size_t)b*512 + bx*8 + g], e);
#pragma unroll
    for (int k=0;k<8;++k) acc[k] += e[k];
  }
#pragma unroll
  for (int k=0;k<8;++k) lds[tq][g][k] = acc[k];
  __syncthreads();
  if (t < 64){
    int gg = t >> 3, c = t & 7;
    float s = 0.f;
#pragma unroll
    for (int q=0;q<32;++q) s += lds[q][gg][c];
    vv[(size_t)m*NN + bx*64 + gg*8 + c] = RVAL / s;
  }
}

// ---------- final: y = Kv ; P = K v_j / y ; per-row loss partial ----------
__global__ __launch_bounds__(256) void loss2_b(const uint* __restrict__ K4base,
                                               const float* __restrict__ vv,
                                               float* __restrict__ accf,
                                               float* __restrict__ Pout, int finalm)
{
  __shared__ float red[4];
  int m = blockIdx.y, i = blockIdx.x, t = threadIdx.x;
  const uint2* row = (const uint2*)(K4base + ((size_t)m*NN + i)*(NN/8));
  const float4* v4 = (const float4*)(vv + (size_t)m*NN);
  uint2 kw = row[t];
  float e[16];
  d4x8(kw.x, e); d4x8(kw.y, e+8);
  float vr[16];
  {
    float4 A=v4[t*4+0], B=v4[t*4+1], C=v4[t*4+2], D=v4[t*4+3];
    vr[0]=A.x; vr[1]=A.y; vr[2]=A.z; vr[3]=A.w;
    vr[4]=B.x; vr[5]=B.y; vr[6]=B.z; vr[7]=B.w;
    vr[8]=C.x; vr[9]=C.y; vr[10]=C.z; vr[11]=C.w;
    vr[12]=D.x; vr[13]=D.y; vr[14]=D.z; vr[15]=D.w;
  }
  float s = 0.f;
#pragma unroll
  for (int k=0;k<16;++k) s += e[k]*vr[k];
  float y = blkSum(s, red);
  float invy = 1.f / y;
  const bool wp = (m==finalm) && (Pout != nullptr);
  const int j0 = t*16;
  float p[16];
#pragma unroll
  for (int k=0;k<16;++k) p[k] = e[k]*vr[k]*invy;
  if (wp){
    float4* pp = (float4*)(Pout + (size_t)i*NN + j0);
#pragma unroll
    for (int q=0;q<4;++q){
      float4 o; o.x=p[q*4]; o.y=p[q*4+1]; o.z=p[q*4+2]; o.w=p[q*4+3];
      pp[q]=o;
    }
  }
  float local = 0.f;
#pragma unroll
  for (int k=0;k<16;++k){
    float d = p[k] - ((j0+k)==i ? 1.f : 0.f);
    local += d*d;
  }
  float tot = blkSum(local, red);
  if (t==0) accf[(size_t)m*NN + i] = tot;
}

// ---------- all four losses + total in one kernel ----------
__global__ __launch_bounds__(256) void lossfin_all(const float* __restrict__ accf,
                                                   float* __restrict__ out)
{
  __shared__ float red[4];
  int t = threadIdx.x;
  float L[4];
#pragma unroll
  for (int m=0;m<4;++m){
    float s = 0.f;
#pragma unroll
    for (int q=0;q<16;++q) s += accf[(size_t)m*NN + t + q*256];
    float tot = blkSum(s, red);
    L[m] = sqrtf(tot);
  }
  if (t==0){
    // m order: {loss_e, loss_ge, loss_eg, loss_g} -> slots {1,3,4,2}
    out[1]=L[0]; out[3]=L[1]; out[4]=L[2]; out[2]=L[3];
    out[0]=L[0]+L[1]+L[2]+L[3];
  }
}

extern "C" void kernel_launch(void* const* d_in, const int* in_sizes, int n_in,
                              void* d_out, int out_size, void* d_ws, size_t ws_size,
                              hipStream_t stream)
{
  (void)in_sizes; (void)n_in; (void)out_size; (void)ws_size;
  const float* f_s  = (const float*)d_in[1];
  const float* l_s  = (const float*)d_in[2];
  const float* f_t  = (const float*)d_in[3];
  const float* l_t  = (const float*)d_in[4];
  const float* W_es = (const float*)d_in[5];
  const float* b_es = (const float*)d_in[6];
  const float* W_et = (const float*)d_in[7];
  const float* b_et = (const float*)d_in[8];
  const float* W_gs = (const float*)d_in[9];
  const float* b_gs = (const float*)d_in[10];
  const float* W_gt = (const float*)d_in[11];
  const float* b_gt = (const float*)d_in[12];
  float* out = (float*)d_out;

  char* ws = (char*)d_ws;
  size_t off = 0;
  auto alloc = [&](size_t nbytes)->void*{
    off = (off + 255) & ~(size_t)255;
    void* p = ws + off; off += nbytes; return p;
  };
  float* f_es = (float*)alloc((size_t)NN*FF*4);
  float* f_et = (float*)alloc((size_t)NN*FF*4);
  unsigned short* f_esb = (unsigned short*)alloc((size_t)NN*FF*2);
  unsigned short* f_etb = (unsigned short*)alloc((size_t)NN*FF*2);
  unsigned short* f_gsb = (unsigned short*)alloc((size_t)NN*FF*2);
  unsigned short* f_gtb = (unsigned short*)alloc((size_t)NN*FF*2);
  float* S_s  = (float*)alloc((size_t)NN*CD*4);
  float* S_t  = (float*)alloc((size_t)NN*CD*4);
  float* w_s  = (float*)alloc(NN*4);
  float* w_t  = (float*)alloc(NN*4);
  int*   idx_s= (int*)alloc(NN*8*4);
  int*   idx_t= (int*)alloc(NN*8*4);
  float* rmax = (float*)alloc(NN*4);
  float* rmin = (float*)alloc(NN*4);
  float* stat = (float*)alloc(64);
  float* v    = (float*)alloc((size_t)4*NN*4);
  float* accf = (float*)alloc((size_t)4*NN*4);
  unsigned short* part = (unsigned short*)alloc((size_t)4*NCH*NN*2);  // 8 MB
  off = (off + 255) & ~(size_t)255;
  unsigned short* stage = (unsigned short*)(ws + off);   // 32 MB bf16 M0 staging
  uint* K4 = (uint*)(stage + (size_t)NN*NN);             // 32 MB 4-bit, 4 matrices
  // knn D (64 MB fp32) overlaps stage + K4 (strictly pre-OT)
  float* Dbuf = (float*)stage;
  // embed scratch also aliases stage (strictly pre-knn)
  float* epart = (float*)stage;                               // KS*NN*FF*4 = 16 MB
  unsigned short* Wt0 = (unsigned short*)((char*)stage + (size_t)KS*NN*FF*4);
  unsigned short* Wt1 = Wt0 + (size_t)FF*EK;                  // 2 MB each

  float* Pout_final = out + 5;
  float* Mout_final = out + 5 + (size_t)NN*NN;

  // ---- embeddings (MFMA split-K) ----
  transposeW<<<EK/64,256,0,stream>>>(W_es, Wt0);
  transposeW<<<EK/64,256,0,stream>>>(W_et, Wt1);
  embed_mfma<<<dim3(64,KS),256,0,stream>>>(f_s, Wt0, epart);
  reduce_l2<<<NN,128,0,stream>>>(epart, b_es, f_es, f_esb);
  embed_mfma<<<dim3(64,KS),256,0,stream>>>(f_t, Wt1, epart);
  reduce_l2<<<NN,128,0,stream>>>(epart, b_et, f_et, f_etb);

  // ---- knn path ----
  softmax_rows<<<NN,128,0,stream>>>(l_s, S_s, w_s);
  softmax_rows<<<NN,128,0,stream>>>(l_t, S_t, w_t);
  cos_gemm<<<dim3(64,64),256,0,stream>>>(S_s, w_s, Dbuf);
  knn_select<<<NN,256,0,stream>>>(Dbuf, idx_s);
  cos_gemm<<<dim3(64,64),256,0,stream>>>(S_t, w_t, Dbuf);
  knn_select<<<NN,256,0,stream>>>(Dbuf, idx_t);
  encoder_kernel<<<NN,128,0,stream>>>(f_es, idx_s, W_gs, b_gs, f_gsb);
  encoder_kernel<<<NN,128,0,stream>>>(f_et, idx_t, W_gt, b_gt, f_gtb);

  // ---- OT: per-matrix build (shared stage), then 4-batched sinkhorn ----
  const unsigned short* ftab[4] = { f_etb, f_gtb, f_etb, f_gtb };
  const unsigned short* fsab[4] = { f_esb, f_esb, f_gtb, f_gsb };

  vinit4<<<(4*NN+255)/256,256,0,stream>>>(v);
  for (int m=0; m<4; ++m){
    gemm_btb_mfma<<<dim3(64,64),256,0,stream>>>(ftab[m], fsab[m], stage);
    rowstat_s<<<NN,256,0,stream>>>(stage, rmax, rmin);
    greduce_s<<<1,256,0,stream>>>(rmax, rmin, stat);
    transform_s<<<256,256,0,stream>>>(stage, K4 + (size_t)m*NN*(NN/8),
        rmax, stat, (m==3) ? Mout_final : (float*)nullptr);
  }
  for (int it=0; it<OT_ITERS; ++it){
    sink_fused<<<dim3(NCH,4),256,0,stream>>>(K4, v, part);
    colfin_b<<<dim3(64,4),256,0,stream>>>(part, v);
  }
  loss2_b<<<dim3(NN,4),256,0,stream>>>(K4, v, accf, Pout_final, 3);
  lossfin_all<<<1,256,0,stream>>>(accf, out);
}